// Round 15
// baseline (153.125 us; speedup 1.0000x reference)
//
#include <hip/hip_runtime.h>
#include <math.h>

constexpr int T  = 2048;
constexpr int Dm = 1024;
constexpr int NH = 16;
constexpr int DH = 64;

typedef unsigned short u16;
typedef _Float16 f16;
typedef f16 f16x8 __attribute__((ext_vector_type(8)));
typedef float f32x4 __attribute__((ext_vector_type(4)));

#define MFMAH(a, b, c) __builtin_amdgcn_mfma_f32_16x16x32_f16((a), (b), (c), 0, 0, 0)

__device__ __forceinline__ float h2f(u16 h) {
    union { u16 u; f16 h; } v; v.u = h; return (float)v.h;
}
__device__ __forceinline__ u16 f2h(float f) {   // RNE via v_cvt_f16_f32
    union { u16 u; f16 h; } v; v.h = (f16)f; return v.u;
}

// ---------------------------------------------------------------------------
__global__ __launch_bounds__(256) void invfreq_kernel(float* __restrict__ invfreq) {
    int c = blockIdx.x * 256 + threadIdx.x;
    if (c < T) {
        float e = (float)(c & ~1) / (float)Dm;
        invfreq[c] = powf(10000.0f, -e);
    }
}

// ---------------------------------------------------------------------------
// Transposed AP table (fp16): APT[s][t] = sin/cos(t*invfreq[s])
// ---------------------------------------------------------------------------
__global__ __launch_bounds__(256) void ap_kernel(const float* __restrict__ invfreq,
                                                 u16* __restrict__ apt) {
    int p = blockIdx.x * 256 + threadIdx.x;   // t-pair index
    int s = blockIdx.y;
    int t = p * 2;
    float f = invfreq[s];
    float v0, v1;
    if (s & 1) { v0 = __cosf((float)t * f); v1 = __cosf((float)(t + 1) * f); }
    else       { v0 = __sinf((float)t * f); v1 = __sinf((float)(t + 1) * f); }
    unsigned int packed = (unsigned int)f2h(v0) | ((unsigned int)f2h(v1) << 16);
    *(unsigned int*)(apt + (size_t)s * T + t) = packed;
}

// ---------------------------------------------------------------------------
// x fp32 -> fp16
// ---------------------------------------------------------------------------
__global__ __launch_bounds__(256) void xconv_kernel(const float* __restrict__ x,
                                                    u16* __restrict__ xh) {
    size_t i = ((size_t)blockIdx.x * 256 + threadIdx.x) * 4;
    float4 v = *(const float4*)(x + i);
    ushort4 hv;
    hv.x = f2h(v.x); hv.y = f2h(v.y); hv.z = f2h(v.z); hv.w = f2h(v.w);
    *(ushort4*)(xh + i) = hv;
}

// ---------------------------------------------------------------------------
// W[h][k][n] fp32 -> Wt[(z,h)][n][k] fp16  (transpose + convert)
// ---------------------------------------------------------------------------
__global__ __launch_bounds__(256) void wtrans_kernel(
    const float* __restrict__ Wq, const float* __restrict__ Wk,
    const float* __restrict__ Wv, u16* __restrict__ Wt)
{
    const int z = blockIdx.z;
    const float* W = (z == 0) ? Wq : (z == 1) ? Wk : Wv;
    const int h = blockIdx.y, kc = blockIdx.x * 64;
    const int tid = threadIdx.x;

    __shared__ float Ls[64][65];
    #pragma unroll
    for (int it = 0; it < 4; ++it) {
        int idx = it * 256 + tid;
        int kl = idx >> 4, n4 = (idx & 15) * 4;
        float4 v = *(const float4*)(W + ((size_t)h * Dm + kc + kl) * DH + n4);
        Ls[n4+0][kl] = v.x; Ls[n4+1][kl] = v.y; Ls[n4+2][kl] = v.z; Ls[n4+3][kl] = v.w;
    }
    __syncthreads();

    const int n = tid >> 2, k16 = (tid & 3) * 16;
    union { u16 u[16]; int4 v[2]; } tmp;
    #pragma unroll
    for (int j = 0; j < 16; ++j) tmp.u[j] = f2h(Ls[n][k16 + j]);
    u16* dst = Wt + (((size_t)z * NH + h) * DH + n) * Dm + kc + k16;
    *(int4*)(dst)     = tmp.v[0];
    *(int4*)(dst + 8) = tmp.v[1];
}

// ---------------------------------------------------------------------------
// Wout fp32 -> fp16
// ---------------------------------------------------------------------------
__global__ __launch_bounds__(256) void wout_conv_kernel(const float* __restrict__ W,
                                                        u16* __restrict__ Wb) {
    size_t i = ((size_t)blockIdx.x * 256 + threadIdx.x) * 4;
    float4 v = *(const float4*)(W + i);
    ushort4 hv;
    hv.x = f2h(v.x); hv.y = f2h(v.y); hv.z = f2h(v.z); hv.w = f2h(v.w);
    *(ushort4*)(Wb + i) = hv;
}

// ---------------------------------------------------------------------------
// Fused QKV projection, fp16 MFMA + swizzled LDS staging (validated r14).
// ---------------------------------------------------------------------------
__global__ __launch_bounds__(256) void proj_mfma(
    const u16* __restrict__ xh, const u16* __restrict__ Wt,
    u16* __restrict__ Qh, u16* __restrict__ Kh, u16* __restrict__ Vt)
{
    __shared__ u16 Xs[4096];
    __shared__ u16 WsQ[4096];
    __shared__ u16 WsK[4096];
    __shared__ u16 WsV[4096];

    const int t0 = blockIdx.x * 64, h = blockIdx.y;
    const int tid = threadIdx.x, w = tid >> 6, lane = tid & 63;
    const int b = lane & 15, a = lane >> 4;

    const int srow = tid >> 2, sc16 = (tid & 3) * 16;
    const int swz = (srow & 7) << 4;
    const int sb0 = (srow * 128 + sc16 * 2) ^ swz;
    const int sb1 = (srow * 128 + sc16 * 2 + 16) ^ swz;

    const u16* WQb = Wt + ((size_t)0 * NH + h) * DH * Dm;
    const u16* WKb = Wt + ((size_t)1 * NH + h) * DH * Dm;
    const u16* WVb = Wt + ((size_t)2 * NH + h) * DH * Dm;

    f32x4 aq[4], ak[4], av[4];
    #pragma unroll
    for (int ct = 0; ct < 4; ++ct) {
        aq[ct] = (f32x4){0.f, 0.f, 0.f, 0.f};
        ak[ct] = (f32x4){0.f, 0.f, 0.f, 0.f};
        av[ct] = (f32x4){0.f, 0.f, 0.f, 0.f};
    }

    for (int kc = 0; kc < Dm; kc += 64) {
        __syncthreads();
        {
            const u16* gx  = xh  + (size_t)(t0 + srow) * Dm + kc + sc16;
            const u16* gwq = WQb + (size_t)srow * Dm + kc + sc16;
            const u16* gwk = WKb + (size_t)srow * Dm + kc + sc16;
            const u16* gwv = WVb + (size_t)srow * Dm + kc + sc16;
            *(int4*)((char*)Xs  + sb0) = *(const int4*)gx;
            *(int4*)((char*)Xs  + sb1) = *(const int4*)(gx + 8);
            *(int4*)((char*)WsQ + sb0) = *(const int4*)gwq;
            *(int4*)((char*)WsQ + sb1) = *(const int4*)(gwq + 8);
            *(int4*)((char*)WsK + sb0) = *(const int4*)gwk;
            *(int4*)((char*)WsK + sb1) = *(const int4*)(gwk + 8);
            *(int4*)((char*)WsV + sb0) = *(const int4*)gwv;
            *(int4*)((char*)WsV + sb1) = *(const int4*)(gwv + 8);
        }
        __syncthreads();

        f16x8 ax[2];
        #pragma unroll
        for (int ks = 0; ks < 2; ++ks) {
            int row = 16 * w + b;
            int byt = (row * 128 + ks * 64 + a * 16) ^ ((row & 7) << 4);
            ax[ks] = *(const f16x8*)((const char*)Xs + byt);
        }
        __builtin_amdgcn_s_setprio(1);
        #pragma unroll
        for (int ct = 0; ct < 4; ++ct) {
            #pragma unroll
            for (int ks = 0; ks < 2; ++ks) {
                int row = 16 * ct + b;
                int byt = (row * 128 + ks * 64 + a * 16) ^ ((row & 7) << 4);
                f16x8 bq = *(const f16x8*)((const char*)WsQ + byt);
                f16x8 bk = *(const f16x8*)((const char*)WsK + byt);
                f16x8 bv = *(const f16x8*)((const char*)WsV + byt);
                aq[ct] = MFMAH(ax[ks], bq, aq[ct]);
                ak[ct] = MFMAH(ax[ks], bk, ak[ct]);
                av[ct] = MFMAH(ax[ks], bv, av[ct]);
            }
        }
        __builtin_amdgcn_s_setprio(0);
    }

    const size_t base = (size_t)h * T * DH;
    #pragma unroll
    for (int ct = 0; ct < 4; ++ct) {
        #pragma unroll
        for (int r = 0; r < 4; ++r) {
            int t = t0 + 16 * w + a * 4 + r;
            size_t off = base + (size_t)t * DH + 16 * ct + b;
            Qh[off] = f2h(aq[ct][r]);
            Kh[off] = f2h(ak[ct][r]);
            Vt[((size_t)h * DH + 16 * ct + b) * T + t] = f2h(av[ct][r]);
        }
    }
}

// ---------------------------------------------------------------------------
// fp16 MFMA flash attention, split-K (2 splits). Double-buffered LDS with
// async-STAGE split (T14): next-tile loads issued BEFORE compute, written to
// the alternate buffer AFTER; one barrier per tile. setprio around MFMA (T5).
// ---------------------------------------------------------------------------
__global__ __launch_bounds__(256) void flash_mfma_split(
    const u16* __restrict__ Qh, const u16* __restrict__ Kh,
    const u16* __restrict__ Vt, const u16* __restrict__ APT,
    u16* __restrict__ Opart, float2* __restrict__ ml)
{
    __shared__ u16 Ks[2][4096];
    __shared__ u16 Vs[2][4096];
    __shared__ u16 Ps[4][1024];

    const int h = blockIdx.y, t0 = blockIdx.x * 64;
    const int split = blockIdx.z;
    const int s_begin = split * (T / 2);
    const int NT = (T / 2) / 64;      // 16 tiles per split
    const int tid = threadIdx.x, w = tid >> 6, lane = tid & 63;
    const int b = lane & 15, a = lane >> 4;

    const size_t hTD = (size_t)h * T * DH;
    const int trow4 = t0 + 16 * w + a * 4;

    const size_t qoff = hTD + (size_t)(t0 + 16*w + b) * DH + a * 8;
    f16x8 qf[2];
    qf[0] = *(const f16x8*)(Qh + qoff);
    qf[1] = *(const f16x8*)(Qh + qoff + 32);

    f32x4 oacc[4];
    float m_run[4], l_run[4];
    #pragma unroll
    for (int i = 0; i < 4; ++i) {
        oacc[i] = (f32x4){0.f, 0.f, 0.f, 0.f};
        m_run[i] = -INFINITY; l_run[i] = 0.f;
    }

    const int srow = tid >> 2, sc16 = (tid & 3) * 16;
    const int swz = (srow & 7) << 4;
    const int sb0 = (srow * 128 + sc16 * 2) ^ swz;
    const int sb1 = (srow * 128 + sc16 * 2 + 16) ^ swz;

    // prologue: stage tile 0 into buffer 0
    int4 kr0, kr1, vr0, vr1;
    {
        const u16* gk = Kh + hTD + (size_t)(s_begin + srow) * DH + sc16;
        const u16* gv = Vt + hTD + (size_t)srow * T + s_begin + sc16;
        kr0 = *(const int4*)gk; kr1 = *(const int4*)(gk + 8);
        vr0 = *(const int4*)gv; vr1 = *(const int4*)(gv + 8);
    }
    *(int4*)((char*)Ks[0] + sb0) = kr0;
    *(int4*)((char*)Ks[0] + sb1) = kr1;
    *(int4*)((char*)Vs[0] + sb0) = vr0;
    *(int4*)((char*)Vs[0] + sb1) = vr1;
    __syncthreads();

    int cur = 0;
    for (int it = 0; it < NT; ++it) {
        const int s0 = s_begin + it * 64;
        const bool has_next = (it + 1 < NT);

        // issue next-tile global loads EARLY (latency hides under compute)
        if (has_next) {
            const int sn = s0 + 64;
            const u16* gk = Kh + hTD + (size_t)(sn + srow) * DH + sc16;
            const u16* gv = Vt + hTD + (size_t)srow * T + sn + sc16;
            kr0 = *(const int4*)gk; kr1 = *(const int4*)(gk + 8);
            vr0 = *(const int4*)gv; vr1 = *(const int4*)(gv + 8);
        }

        // AP bias loads issued first: latency hides under the QK^T MFMAs
        ushort4 ap4[4];
        #pragma unroll
        for (int ct = 0; ct < 4; ++ct)
            ap4[ct] = *(const ushort4*)(APT + (size_t)(s0 + b + 16 * ct) * T + trow4);

        f32x4 acc[4];
        #pragma unroll
        for (int ct = 0; ct < 4; ++ct) acc[ct] = (f32x4){0.f, 0.f, 0.f, 0.f};
        __builtin_amdgcn_s_setprio(1);
        #pragma unroll
        for (int ct = 0; ct < 4; ++ct) {
            #pragma unroll
            for (int ks = 0; ks < 2; ++ks) {
                int row = 16 * ct + b;
                int byt = (row * 128 + ks * 64 + a * 16) ^ ((row & 7) << 4);
                f16x8 kf = *(const f16x8*)((const char*)Ks[cur] + byt);
                acc[ct] = MFMAH(qf[ks], kf, acc[ct]);
            }
        }
        __builtin_amdgcn_s_setprio(0);

        #pragma unroll
        for (int ct = 0; ct < 4; ++ct) {
            const u16* apu = (const u16*)&ap4[ct];
            #pragma unroll
            for (int r = 0; r < 4; ++r)
                acc[ct][r] += h2f(apu[r]);
        }

        #pragma unroll
        for (int r = 0; r < 4; ++r) {
            float mx = fmaxf(fmaxf(acc[0][r], acc[1][r]), fmaxf(acc[2][r], acc[3][r]));
            #pragma unroll
            for (int msk = 8; msk > 0; msk >>= 1) mx = fmaxf(mx, __shfl_xor(mx, msk));
            float mnew  = fmaxf(m_run[r], mx);
            float alpha = __expf(m_run[r] - mnew);   // first tile: 0
            float p0 = __expf(acc[0][r] - mnew);
            float p1 = __expf(acc[1][r] - mnew);
            float p2 = __expf(acc[2][r] - mnew);
            float p3 = __expf(acc[3][r] - mnew);
            float rs = p0 + p1 + p2 + p3;
            #pragma unroll
            for (int msk = 8; msk > 0; msk >>= 1) rs += __shfl_xor(rs, msk);
            l_run[r] = l_run[r] * alpha + rs;
            m_run[r] = mnew;
            oacc[0][r] *= alpha; oacc[1][r] *= alpha;
            oacc[2][r] *= alpha; oacc[3][r] *= alpha;
            int rl = a * 4 + r;
            int rbase = rl * 128, rswz = (rl & 7) << 4;
            *(u16*)((char*)Ps[w] + ((rbase + (b     ) * 2) ^ rswz)) = f2h(p0);
            *(u16*)((char*)Ps[w] + ((rbase + (b + 16) * 2) ^ rswz)) = f2h(p1);
            *(u16*)((char*)Ps[w] + ((rbase + (b + 32) * 2) ^ rswz)) = f2h(p2);
            *(u16*)((char*)Ps[w] + ((rbase + (b + 48) * 2) ^ rswz)) = f2h(p3);
        }

        f16x8 pa[2];
        #pragma unroll
        for (int ks = 0; ks < 2; ++ks) {
            int byt = (b * 128 + ks * 64 + a * 16) ^ ((b & 7) << 4);
            pa[ks] = *(const f16x8*)((const char*)Ps[w] + byt);
        }
        __builtin_amdgcn_s_setprio(1);
        #pragma unroll
        for (int dt = 0; dt < 4; ++dt) {
            #pragma unroll
            for (int ks = 0; ks < 2; ++ks) {
                int row = 16 * dt + b;
                int byt = (row * 128 + ks * 64 + a * 16) ^ ((row & 7) << 4);
                f16x8 vf = *(const f16x8*)((const char*)Vs[cur] + byt);
                oacc[dt] = MFMAH(pa[ks], vf, oacc[dt]);
            }
        }
        __builtin_amdgcn_s_setprio(0);

        // write next tile into the alternate buffer, then one barrier
        if (has_next) {
            *(int4*)((char*)Ks[cur ^ 1] + sb0) = kr0;
            *(int4*)((char*)Ks[cur ^ 1] + sb1) = kr1;
            *(int4*)((char*)Vs[cur ^ 1] + sb0) = vr0;
            *(int4*)((char*)Vs[cur ^ 1] + sb1) = vr1;
            __syncthreads();
        }
        cur ^= 1;
    }

    const size_t pbase = ((size_t)split * NH + h) * T;
    #pragma unroll
    for (int r = 0; r < 4; ++r) {
        int t = trow4 + r;
        #pragma unroll
        for (int dt = 0; dt < 4; ++dt)
            Opart[(pbase + t) * DH + 16 * dt + b] = f2h(oacc[dt][r]);
        if (b == 0) ml[pbase + t] = make_float2(m_run[r], l_run[r]);
    }
}

// ---------------------------------------------------------------------------
// Combine split-K partials; stores (m*, 1/L) for head 15 softmax fusion.
// ---------------------------------------------------------------------------
__global__ __launch_bounds__(256) void flash_combine(
    const u16* __restrict__ Opart, const float2* __restrict__ ml,
    u16* __restrict__ Ych, float2* __restrict__ mlfinal)
{
    int idx = blockIdx.x * 256 + threadIdx.x;          // NH*T*8 total
    int h = idx >> 14;
    int rem = idx & 16383;
    int t = rem >> 3;
    int d8 = (rem & 7) * 8;

    const size_t r0 = ((size_t)0 * NH + h) * T + t;
    const size_t r1 = ((size_t)1 * NH + h) * T + t;
    float2 ml0 = ml[r0], ml1 = ml[r1];
    float m = fmaxf(ml0.x, ml1.x);
    float w0 = __expf(ml0.x - m), w1 = __expf(ml1.x - m);
    float inv = 1.f / (w0 * ml0.y + w1 * ml1.y);
    if (h == NH - 1 && d8 == 0) mlfinal[t] = make_float2(m, inv);
    w0 *= inv; w1 *= inv;

    union { u16 u[8]; int4 v; } o0, o1, yo;
    o0.v = *(const int4*)(Opart + r0 * DH + d8);
    o1.v = *(const int4*)(Opart + r1 * DH + d8);
    #pragma unroll
    for (int j = 0; j < 8; ++j)
        yo.u[j] = f2h(h2f(o0.u[j]) * w0 + h2f(o1.u[j]) * w1);
    *(int4*)(Ych + (size_t)t * Dm + h * DH + d8) = yo.v;
}

// ---------------------------------------------------------------------------
// Head-15 attention map, softmax fused: P = exp(S - m*) * (1/L).
// S bitwise-identical to flash's (same fp16 MFMA on same fragments).
// ---------------------------------------------------------------------------
__global__ __launch_bounds__(256) void score_mfma(
    const u16* __restrict__ Qh, const u16* __restrict__ Kh,
    const u16* __restrict__ APT, const float2* __restrict__ mlf,
    float* __restrict__ S)
{
    __shared__ u16 Ks[4096];

    const int h = NH - 1;
    const int s0 = blockIdx.x * 64, t0 = blockIdx.y * 64;
    const int tid = threadIdx.x, w = tid >> 6, lane = tid & 63;
    const int b = lane & 15, a = lane >> 4;
    const size_t hTD = (size_t)h * T * DH;
    const int trow4 = t0 + 16 * w + a * 4;

    {
        const int srow = tid >> 2, sc16 = (tid & 3) * 16;
        const int swz = (srow & 7) << 4;
        const int sb0 = (srow * 128 + sc16 * 2) ^ swz;
        const int sb1 = (srow * 128 + sc16 * 2 + 16) ^ swz;
        const u16* gk = Kh + hTD + (size_t)(s0 + srow) * DH + sc16;
        *(int4*)((char*)Ks + sb0) = *(const int4*)gk;
        *(int4*)((char*)Ks + sb1) = *(const int4*)(gk + 8);
    }

    const size_t qoff = hTD + (size_t)(t0 + 16*w + b) * DH + a * 8;
    f16x8 qf[2];
    qf[0] = *(const f16x8*)(Qh + qoff);
    qf[1] = *(const f16x8*)(Qh + qoff + 32);
    __syncthreads();

    ushort4 ap4[4];
    #pragma unroll
    for (int ct = 0; ct < 4; ++ct)
        ap4[ct] = *(const ushort4*)(APT + (size_t)(s0 + b + 16 * ct) * T + trow4);
    float2 f[4];
    #pragma unroll
    for (int r = 0; r < 4; ++r) f[r] = mlf[trow4 + r];

    f32x4 acc[4];
    #pragma unroll
    for (int ct = 0; ct < 4; ++ct) acc[ct] = (f32x4){0.f, 0.f, 0.f, 0.f};
    #pragma unroll
    for (int ct = 0; ct < 4; ++ct) {
        #pragma unroll
        for (int ks = 0; ks < 2; ++ks) {
            int row = 16 * ct + b;
            int byt = (row * 128 + ks * 64 + a * 16) ^ ((row & 7) << 4);
            f16x8 kf = *(const f16x8*)((const char*)Ks + byt);
            acc[ct] = MFMAH(qf[ks], kf, acc[ct]);
        }
    }

    #pragma unroll
    for (int ct = 0; ct < 4; ++ct) {
        const u16* apu = (const u16*)&ap4[ct];
        #pragma unroll
        for (int r = 0; r < 4; ++r) {
            float sval = acc[ct][r] + h2f(apu[r]);
            S[(size_t)(trow4 + r) * T + s0 + 16 * ct + b] =
                __expf(sval - f[r].x) * f[r].y;
        }
    }
}

// ---------------------------------------------------------------------------
// y = Ych(fp16) @ Woutb(fp16)^T via MFMA with LDS staging
// ---------------------------------------------------------------------------
__global__ __launch_bounds__(256) void gemm_out_mfma(
    const u16* __restrict__ Ych, const u16* __restrict__ Wb,
    float* __restrict__ y)
{
    __shared__ u16 As[4096];
    __shared__ u16 Bs[4096];

    const int n0 = blockIdx.x * 64, t0 = blockIdx.y * 64;
    const int tid = threadIdx.x, w = tid >> 6, lane = tid & 63;
    const int b = lane & 15, a = lane >> 4;

    const int srow = tid >> 2, sc16 = (tid & 3) * 16;
    const int swz = (srow & 7) << 4;
    const int sb0 = (srow * 128 + sc16 * 2) ^ swz;
    const int sb1 = (srow * 128 + sc16 * 2 + 16) ^ swz;

    f32x4 acc[4];
    #pragma unroll
    for (int ct = 0; ct < 4; ++ct) acc[ct] = (f32x4){0.f, 0.f, 0.f, 0.f};

    for (int kc = 0; kc < Dm; kc += 64) {
        __syncthreads();
        {
            const u16* ga = Ych + (size_t)(t0 + srow) * Dm + kc + sc16;
            const u16* gb = Wb  + (size_t)(n0 + srow) * Dm + kc + sc16;
            *(int4*)((char*)As + sb0) = *(const int4*)ga;
            *(int4*)((char*)As + sb1) = *(const int4*)(ga + 8);
            *(int4*)((char*)Bs + sb0) = *(const int4*)gb;
            *(int4*)((char*)Bs + sb1) = *(const int4*)(gb + 8);
        }
        __syncthreads();

        f16x8 af[2];
        #pragma unroll
        for (int ks = 0; ks < 2; ++ks) {
            int row = 16 * w + b;
            int byt = (row * 128 + ks * 64 + a * 16) ^ ((row & 7) << 4);
            af[ks] = *(const f16x8*)((const char*)As + byt);
        }
        __builtin_amdgcn_s_setprio(1);
        #pragma unroll
        for (int ct = 0; ct < 4; ++ct) {
            #pragma unroll
            for (int ks = 0; ks < 2; ++ks) {
                int row = 16 * ct + b;
                int byt = (row * 128 + ks * 64 + a * 16) ^ ((row & 7) << 4);
                f16x8 bw = *(const f16x8*)((const char*)Bs + byt);
                acc[ct] = MFMAH(af[ks], bw, acc[ct]);
            }
        }
        __builtin_amdgcn_s_setprio(0);
    }

    #pragma unroll
    for (int r = 0; r < 4; ++r) {
        int t = t0 + 16 * w + a * 4 + r;
        #pragma unroll
        for (int ct = 0; ct < 4; ++ct)
            y[(size_t)t * Dm + n0 + 16 * ct + b] = acc[ct][r];
    }
}

// ---------------------------------------------------------------------------
extern "C" void kernel_launch(void* const* d_in, const int* in_sizes, int n_in,
                              void* d_out, int out_size, void* d_ws, size_t ws_size,
                              hipStream_t stream)
{
    const float* x    = (const float*)d_in[0];
    const float* Wq   = (const float*)d_in[1];
    const float* Wk   = (const float*)d_in[2];
    const float* Wv   = (const float*)d_in[3];
    const float* Wout = (const float*)d_in[4];

    float* out      = (float*)d_out;
    float* y_out    = out;
    float* attn_out = out + (long)T * Dm;     // written LAST -> usable scratch

    // ---- workspace layout (~26 MB; 34.3 MB proven) ----
    char* ws = (char*)d_ws;
    const size_t MB = 1024 * 1024;
    float* invfreq = (float*)ws;                       // 8 KB
    u16* Qh = (u16*)(ws + 8192);                       // 4 MB
    u16* Kh = (u16*)(ws + 8192 + 4 * MB);              // 4 MB
    u16* Vt = (u16*)(ws + 8192 + 8 * MB);              // 4 MB
    char* C = ws + 8192 + 12 * MB;
    u16* xh  = (u16*)(C);                              // phase 1: 4 MB
    u16* Wtb = (u16*)(C + 4 * MB);                     //          6 MB
    u16* APt   = (u16*)(C);                            // phase 2: 8 MB
    u16* Ych   = (u16*)(C + 8 * MB);                   //          4 MB
    u16* Woutb = (u16*)(C + 12 * MB);                  //          2 MB
    float2* mlfinal = (float2*)(C + 14 * MB);          //          16 KB
    // split-K partials in d_out attn region (overwritten later by score):
    u16*    Opart = (u16*)attn_out;                    // 8 MB
    float2* mlbuf = (float2*)((char*)attn_out + 8 * MB); // 512 KB
    (void)ws_size;

    invfreq_kernel<<<dim3(8), dim3(256), 0, stream>>>(invfreq);

    xconv_kernel<<<dim3((T * Dm / 4) / 256), dim3(256), 0, stream>>>(x, xh);
    wtrans_kernel<<<dim3(Dm / 64, NH, 3), dim3(256), 0, stream>>>(Wq, Wk, Wv, Wtb);

    proj_mfma<<<dim3(T / 64, NH), dim3(256), 0, stream>>>(xh, Wtb, Qh, Kh, Vt);

    ap_kernel<<<dim3(T / 512, T), dim3(256), 0, stream>>>(invfreq, APt);
    wout_conv_kernel<<<dim3((Dm * Dm / 4) / 256), dim3(256), 0, stream>>>(Wout, Woutb);

    flash_mfma_split<<<dim3(T / 64, NH, 2), dim3(256), 0, stream>>>(
        Qh, Kh, Vt, APt, Opart, mlbuf);
    flash_combine<<<dim3(NH * T * 8 / 256), dim3(256), 0, stream>>>(
        Opart, mlbuf, Ych, mlfinal);

    // head-15 attention map with fused softmax (overwrites scratch region)
    score_mfma<<<dim3(T / 64, T / 64), dim3(256), 0, stream>>>(
        Qh, Kh, APt, mlfinal, attn_out);

    gemm_out_mfma<<<dim3(Dm / 64, T / 64), dim3(256), 0, stream>>>(Ych, Woutb, y_out);
}

// Round 18
// 124.366 us; speedup vs baseline: 1.2313x; 1.2313x over previous
//
#include <hip/hip_runtime.h>
#include <math.h>

constexpr int T  = 2048;
constexpr int Dm = 1024;
constexpr int NH = 16;
constexpr int DH = 64;

typedef unsigned short u16;
typedef _Float16 f16;
typedef f16 f16x8 __attribute__((ext_vector_type(8)));
typedef __fp16 fp16x2 __attribute__((ext_vector_type(2)));   // cvt_pkrtz native type
typedef float f32x4 __attribute__((ext_vector_type(4)));

#define MFMAH(a, b, c) __builtin_amdgcn_mfma_f32_16x16x32_f16((a), (b), (c), 0, 0, 0)

__device__ __forceinline__ float h2f(u16 h) {
    union { u16 u; f16 h; } v; v.u = h; return (float)v.h;
}
__device__ __forceinline__ u16 f2h(float f) {
    union { u16 u; f16 h; } v; v.h = (f16)f; return v.u;
}

// ---------------------------------------------------------------------------
__global__ __launch_bounds__(256) void invfreq_kernel(float* __restrict__ invfreq) {
    int c = blockIdx.x * 256 + threadIdx.x;
    if (c < T) {
        float e = (float)(c & ~1) / (float)Dm;
        invfreq[c] = powf(10000.0f, -e);
    }
}

// ---------------------------------------------------------------------------
// AP table [t][s] (fp16): AP[t][s] = sin/cos(t*invfreq[s])
// ---------------------------------------------------------------------------
__global__ __launch_bounds__(256) void ap_kernel(const float* __restrict__ invfreq,
                                                 u16* __restrict__ ap) {
    int p = blockIdx.x * 256 + threadIdx.x;   // s-pair index
    int t = blockIdx.y;
    int s = p * 2;
    float f = invfreq[s];
    float sn, cs;
    __sincosf((float)t * f, &sn, &cs);
    unsigned int packed = (unsigned int)f2h(sn) | ((unsigned int)f2h(cs) << 16);
    *(unsigned int*)(ap + (size_t)t * T + s) = packed;
}

// ---------------------------------------------------------------------------
__global__ __launch_bounds__(256) void xconv_kernel(const float* __restrict__ x,
                                                    u16* __restrict__ xh) {
    size_t i = ((size_t)blockIdx.x * 256 + threadIdx.x) * 4;
    float4 v = *(const float4*)(x + i);
    ushort4 hv;
    hv.x = f2h(v.x); hv.y = f2h(v.y); hv.z = f2h(v.z); hv.w = f2h(v.w);
    *(ushort4*)(xh + i) = hv;
}

// ---------------------------------------------------------------------------
__global__ __launch_bounds__(256) void wtrans_kernel(
    const float* __restrict__ Wq, const float* __restrict__ Wk,
    const float* __restrict__ Wv, u16* __restrict__ Wt)
{
    const int z = blockIdx.z;
    const float* W = (z == 0) ? Wq : (z == 1) ? Wk : Wv;
    const int h = blockIdx.y, kc = blockIdx.x * 64;
    const int tid = threadIdx.x;

    __shared__ float Ls[64][65];
    #pragma unroll
    for (int it = 0; it < 4; ++it) {
        int idx = it * 256 + tid;
        int kl = idx >> 4, n4 = (idx & 15) * 4;
        float4 v = *(const float4*)(W + ((size_t)h * Dm + kc + kl) * DH + n4);
        Ls[n4+0][kl] = v.x; Ls[n4+1][kl] = v.y; Ls[n4+2][kl] = v.z; Ls[n4+3][kl] = v.w;
    }
    __syncthreads();

    const int n = tid >> 2, k16 = (tid & 3) * 16;
    union { u16 u[16]; int4 v[2]; } tmp;
    #pragma unroll
    for (int j = 0; j < 16; ++j) tmp.u[j] = f2h(Ls[n][k16 + j]);
    u16* dst = Wt + (((size_t)z * NH + h) * DH + n) * Dm + kc + k16;
    *(int4*)(dst)     = tmp.v[0];
    *(int4*)(dst + 8) = tmp.v[1];
}

// ---------------------------------------------------------------------------
__global__ __launch_bounds__(256) void wout_conv_kernel(const float* __restrict__ W,
                                                        u16* __restrict__ Wb) {
    size_t i = ((size_t)blockIdx.x * 256 + threadIdx.x) * 4;
    float4 v = *(const float4*)(W + i);
    ushort4 hv;
    hv.x = f2h(v.x); hv.y = f2h(v.y); hv.z = f2h(v.z); hv.w = f2h(v.w);
    *(ushort4*)(Wb + i) = hv;
}

// ---------------------------------------------------------------------------
// Fused QKV projection, fp16 MFMA + swizzled LDS staging (validated r14/r15).
// ---------------------------------------------------------------------------
__global__ __launch_bounds__(256) void proj_mfma(
    const u16* __restrict__ xh, const u16* __restrict__ Wt,
    u16* __restrict__ Qh, u16* __restrict__ Kh, u16* __restrict__ Vt)
{
    __shared__ u16 Xs[4096];
    __shared__ u16 WsQ[4096];
    __shared__ u16 WsK[4096];
    __shared__ u16 WsV[4096];

    const int t0 = blockIdx.x * 64, h = blockIdx.y;
    const int tid = threadIdx.x, w = tid >> 6, lane = tid & 63;
    const int b = lane & 15, a = lane >> 4;

    const int srow = tid >> 2, sc16 = (tid & 3) * 16;
    const int swz = (srow & 7) << 4;
    const int sb0 = (srow * 128 + sc16 * 2) ^ swz;
    const int sb1 = (srow * 128 + sc16 * 2 + 16) ^ swz;

    const u16* WQb = Wt + ((size_t)0 * NH + h) * DH * Dm;
    const u16* WKb = Wt + ((size_t)1 * NH + h) * DH * Dm;
    const u16* WVb = Wt + ((size_t)2 * NH + h) * DH * Dm;

    f32x4 aq[4], ak[4], av[4];
    #pragma unroll
    for (int ct = 0; ct < 4; ++ct) {
        aq[ct] = (f32x4){0.f, 0.f, 0.f, 0.f};
        ak[ct] = (f32x4){0.f, 0.f, 0.f, 0.f};
        av[ct] = (f32x4){0.f, 0.f, 0.f, 0.f};
    }

    for (int kc = 0; kc < Dm; kc += 64) {
        __syncthreads();
        {
            const u16* gx  = xh  + (size_t)(t0 + srow) * Dm + kc + sc16;
            const u16* gwq = WQb + (size_t)srow * Dm + kc + sc16;
            const u16* gwk = WKb + (size_t)srow * Dm + kc + sc16;
            const u16* gwv = WVb + (size_t)srow * Dm + kc + sc16;
            *(int4*)((char*)Xs  + sb0) = *(const int4*)gx;
            *(int4*)((char*)Xs  + sb1) = *(const int4*)(gx + 8);
            *(int4*)((char*)WsQ + sb0) = *(const int4*)gwq;
            *(int4*)((char*)WsQ + sb1) = *(const int4*)(gwq + 8);
            *(int4*)((char*)WsK + sb0) = *(const int4*)gwk;
            *(int4*)((char*)WsK + sb1) = *(const int4*)(gwk + 8);
            *(int4*)((char*)WsV + sb0) = *(const int4*)gwv;
            *(int4*)((char*)WsV + sb1) = *(const int4*)(gwv + 8);
        }
        __syncthreads();

        f16x8 ax[2];
        #pragma unroll
        for (int ks = 0; ks < 2; ++ks) {
            int row = 16 * w + b;
            int byt = (row * 128 + ks * 64 + a * 16) ^ ((row & 7) << 4);
            ax[ks] = *(const f16x8*)((const char*)Xs + byt);
        }
        __builtin_amdgcn_s_setprio(1);
        #pragma unroll
        for (int ct = 0; ct < 4; ++ct) {
            #pragma unroll
            for (int ks = 0; ks < 2; ++ks) {
                int row = 16 * ct + b;
                int byt = (row * 128 + ks * 64 + a * 16) ^ ((row & 7) << 4);
                f16x8 bq = *(const f16x8*)((const char*)WsQ + byt);
                f16x8 bk = *(const f16x8*)((const char*)WsK + byt);
                f16x8 bv = *(const f16x8*)((const char*)WsV + byt);
                aq[ct] = MFMAH(ax[ks], bq, aq[ct]);
                ak[ct] = MFMAH(ax[ks], bk, ak[ct]);
                av[ct] = MFMAH(ax[ks], bv, av[ct]);
            }
        }
        __builtin_amdgcn_s_setprio(0);
    }

    const size_t base = (size_t)h * T * DH;
    #pragma unroll
    for (int ct = 0; ct < 4; ++ct) {
        #pragma unroll
        for (int r = 0; r < 4; ++r) {
            int t = t0 + 16 * w + a * 4 + r;
            size_t off = base + (size_t)t * DH + 16 * ct + b;
            Qh[off] = f2h(aq[ct][r]);
            Kh[off] = f2h(ak[ct][r]);
            Vt[((size_t)h * DH + 16 * ct + b) * T + t] = f2h(av[ct][r]);
        }
    }
}

// ---------------------------------------------------------------------------
// fp16 MFMA flash attention, split-K (2 splits), SWAPPED operands:
// QK^T = MFMAH(kf, qf) -> lane owns ONE q-row (t = t0+16w+b), s along regs.
// Softmax: scalar row ops + 2 shuffles (was 32). PV = MFMAH(vf, pa).
// r14 single-buffer barrier structure (dbuf regressed in r15).
// ---------------------------------------------------------------------------
__global__ __launch_bounds__(256) void flash_mfma_split(
    const u16* __restrict__ Qh, const u16* __restrict__ Kh,
    const u16* __restrict__ Vt, const u16* __restrict__ AP,
    u16* __restrict__ Opart, float2* __restrict__ ml)
{
    __shared__ u16 Ks[4096];
    __shared__ u16 Vs[4096];
    __shared__ u16 Ps[4][1024];

    const int h = blockIdx.y, t0 = blockIdx.x * 64;
    const int split = blockIdx.z;
    const int s_begin = split * (T / 2), s_end = s_begin + T / 2;
    const int tid = threadIdx.x, w = tid >> 6, lane = tid & 63;
    const int b = lane & 15, a = lane >> 4;

    const size_t hTD = (size_t)h * T * DH;
    const int trow = t0 + 16 * w + b;          // this lane's q-row

    const size_t qoff = hTD + (size_t)trow * DH + a * 8;
    f16x8 qf[2];
    qf[0] = *(const f16x8*)(Qh + qoff);
    qf[1] = *(const f16x8*)(Qh + qoff + 32);

    f32x4 oacc[4];                              // O[t=trow][d = 16dt+4a+r]
    float m_run = -INFINITY, l_run = 0.f;
    #pragma unroll
    for (int i = 0; i < 4; ++i) oacc[i] = (f32x4){0.f, 0.f, 0.f, 0.f};

    const int srow = tid >> 2, sc16 = (tid & 3) * 16;
    const int swz = (srow & 7) << 4;
    const int sb0 = (srow * 128 + sc16 * 2) ^ swz;
    const int sb1 = (srow * 128 + sc16 * 2 + 16) ^ swz;

    const u16* aprow = AP + (size_t)trow * T;   // AP[t][.], t fixed per lane

    for (int s0 = s_begin; s0 < s_end; s0 += 64) {
        __syncthreads();
        {
            const u16* gk = Kh + hTD + (size_t)(s0 + srow) * DH + sc16;
            const u16* gv = Vt + hTD + (size_t)srow * T + s0 + sc16;
            *(int4*)((char*)Ks + sb0) = *(const int4*)gk;
            *(int4*)((char*)Ks + sb1) = *(const int4*)(gk + 8);
            *(int4*)((char*)Vs + sb0) = *(const int4*)gv;
            *(int4*)((char*)Vs + sb1) = *(const int4*)(gv + 8);
        }
        __syncthreads();

        // AP bias loads issued early (contiguous in s for this lane's row)
        ushort4 ap4[4];
        #pragma unroll
        for (int ct = 0; ct < 4; ++ct)
            ap4[ct] = *(const ushort4*)(aprow + s0 + 16 * ct + 4 * a);

        // S^T tile: acc[ct][r] = S[t=trow][s = s0 + 16ct + 4a + r]
        f32x4 acc[4];
        #pragma unroll
        for (int ct = 0; ct < 4; ++ct) acc[ct] = (f32x4){0.f, 0.f, 0.f, 0.f};
        #pragma unroll
        for (int ct = 0; ct < 4; ++ct) {
            #pragma unroll
            for (int ks = 0; ks < 2; ++ks) {
                int row = 16 * ct + b;
                int byt = (row * 128 + ks * 64 + a * 16) ^ ((row & 7) << 4);
                f16x8 kf = *(const f16x8*)((const char*)Ks + byt);
                acc[ct] = MFMAH(kf, qf[ks], acc[ct]);   // swapped
            }
        }

        #pragma unroll
        for (int ct = 0; ct < 4; ++ct) {
            const u16* apu = (const u16*)&ap4[ct];
            #pragma unroll
            for (int r = 0; r < 4; ++r)
                acc[ct][r] += h2f(apu[r]);
        }

        // per-lane row softmax: scalar over 16 regs + 2 cross-lane shuffles
        float mx = acc[0][0];
        #pragma unroll
        for (int ct = 0; ct < 4; ++ct)
            #pragma unroll
            for (int r = 0; r < 4; ++r) mx = fmaxf(mx, acc[ct][r]);
        mx = fmaxf(mx, __shfl_xor(mx, 16));
        mx = fmaxf(mx, __shfl_xor(mx, 32));

        float mnew  = fmaxf(m_run, mx);
        float alpha = __expf(m_run - mnew);     // first tile: exp(-inf)=0
        float rs = 0.f;
        #pragma unroll
        for (int ct = 0; ct < 4; ++ct) {
            #pragma unroll
            for (int r = 0; r < 4; ++r) {
                float p = __expf(acc[ct][r] - mnew);
                acc[ct][r] = p;
                rs += p;
            }
        }
        rs += __shfl_xor(rs, 16);
        rs += __shfl_xor(rs, 32);
        l_run = l_run * alpha + rs;
        m_run = mnew;
        #pragma unroll
        for (int dt = 0; dt < 4; ++dt) {
            oacc[dt][0] *= alpha; oacc[dt][1] *= alpha;
            oacc[dt][2] *= alpha; oacc[dt][3] *= alpha;
        }

        // P -> Ps[w]: row b (=t), cols 16ct+4a..+3; packed 8B writes
        #pragma unroll
        for (int ct = 0; ct < 4; ++ct) {
            union { fp16x2 h[2]; int2 i2; } u;
            u.h[0] = __builtin_amdgcn_cvt_pkrtz(acc[ct][0], acc[ct][1]);
            u.h[1] = __builtin_amdgcn_cvt_pkrtz(acc[ct][2], acc[ct][3]);
            int byt = (b * 128 + ct * 32 + a * 8) ^ ((b & 7) << 4);
            *(int2*)((char*)Ps[w] + byt) = u.i2;
        }

        // PV: B = P (row=t lane-local), A = V^T
        f16x8 pa[2];
        #pragma unroll
        for (int ks = 0; ks < 2; ++ks) {
            int byt = (b * 128 + ks * 64 + a * 16) ^ ((b & 7) << 4);
            pa[ks] = *(const f16x8*)((const char*)Ps[w] + byt);
        }
        #pragma unroll
        for (int dt = 0; dt < 4; ++dt) {
            #pragma unroll
            for (int ks = 0; ks < 2; ++ks) {
                int row = 16 * dt + b;
                int byt = (row * 128 + ks * 64 + a * 16) ^ ((row & 7) << 4);
                f16x8 vf = *(const f16x8*)((const char*)Vs + byt);
                oacc[dt] = MFMAH(vf, pa[ks], oacc[dt]);   // swapped
            }
        }
    }

    const size_t pbase = ((size_t)split * NH + h) * T;
    #pragma unroll
    for (int dt = 0; dt < 4; ++dt) {
        ushort4 ov;
        ov.x = f2h(oacc[dt][0]); ov.y = f2h(oacc[dt][1]);
        ov.z = f2h(oacc[dt][2]); ov.w = f2h(oacc[dt][3]);
        *(ushort4*)(Opart + (pbase + trow) * DH + 16 * dt + 4 * a) = ov;
    }
    if (a == 0) ml[pbase + trow] = make_float2(m_run, l_run);
}

// ---------------------------------------------------------------------------
// Combine split-K partials; stores (m*, 1/L) for head 15 softmax fusion.
// ---------------------------------------------------------------------------
__global__ __launch_bounds__(256) void flash_combine(
    const u16* __restrict__ Opart, const float2* __restrict__ ml,
    u16* __restrict__ Ych, float2* __restrict__ mlfinal)
{
    int idx = blockIdx.x * 256 + threadIdx.x;          // NH*T*8 total
    int h = idx >> 14;
    int rem = idx & 16383;
    int t = rem >> 3;
    int d8 = (rem & 7) * 8;

    const size_t r0 = ((size_t)0 * NH + h) * T + t;
    const size_t r1 = ((size_t)1 * NH + h) * T + t;
    float2 ml0 = ml[r0], ml1 = ml[r1];
    float m = fmaxf(ml0.x, ml1.x);
    float w0 = __expf(ml0.x - m), w1 = __expf(ml1.x - m);
    float inv = 1.f / (w0 * ml0.y + w1 * ml1.y);
    if (h == NH - 1 && d8 == 0) mlfinal[t] = make_float2(m, inv);
    w0 *= inv; w1 *= inv;

    union { u16 u[8]; int4 v; } o0, o1, yo;
    o0.v = *(const int4*)(Opart + r0 * DH + d8);
    o1.v = *(const int4*)(Opart + r1 * DH + d8);
    #pragma unroll
    for (int j = 0; j < 8; ++j)
        yo.u[j] = f2h(h2f(o0.u[j]) * w0 + h2f(o1.u[j]) * w1);
    *(int4*)(Ych + (size_t)t * Dm + h * DH + d8) = yo.v;
}

// ---------------------------------------------------------------------------
// Head-15 attention map, swapped operands + fused softmax; float4 stores.
// ---------------------------------------------------------------------------
__global__ __launch_bounds__(256) void score_mfma(
    const u16* __restrict__ Qh, const u16* __restrict__ Kh,
    const u16* __restrict__ AP, const float2* __restrict__ mlf,
    float* __restrict__ S)
{
    __shared__ u16 Ks[4096];

    const int h = NH - 1;
    const int s0 = blockIdx.x * 64, t0 = blockIdx.y * 64;
    const int tid = threadIdx.x, w = tid >> 6, lane = tid & 63;
    const int b = lane & 15, a = lane >> 4;
    const size_t hTD = (size_t)h * T * DH;
    const int trow = t0 + 16 * w + b;

    {
        const int srow = tid >> 2, sc16 = (tid & 3) * 16;
        const int swz = (srow & 7) << 4;
        const int sb0 = (srow * 128 + sc16 * 2) ^ swz;
        const int sb1 = (srow * 128 + sc16 * 2 + 16) ^ swz;
        const u16* gk = Kh + hTD + (size_t)(s0 + srow) * DH + sc16;
        *(int4*)((char*)Ks + sb0) = *(const int4*)gk;
        *(int4*)((char*)Ks + sb1) = *(const int4*)(gk + 8);
    }

    const size_t qoff = hTD + (size_t)trow * DH + a * 8;
    f16x8 qf[2];
    qf[0] = *(const f16x8*)(Qh + qoff);
    qf[1] = *(const f16x8*)(Qh + qoff + 32);
    __syncthreads();

    ushort4 ap4[4];
    #pragma unroll
    for (int ct = 0; ct < 4; ++ct)
        ap4[ct] = *(const ushort4*)(AP + (size_t)trow * T + s0 + 16 * ct + 4 * a);
    float2 fml = mlf[trow];

    f32x4 acc[4];
    #pragma unroll
    for (int ct = 0; ct < 4; ++ct) acc[ct] = (f32x4){0.f, 0.f, 0.f, 0.f};
    #pragma unroll
    for (int ct = 0; ct < 4; ++ct) {
        #pragma unroll
        for (int ks = 0; ks < 2; ++ks) {
            int row = 16 * ct + b;
            int byt = (row * 128 + ks * 64 + a * 16) ^ ((row & 7) << 4);
            f16x8 kf = *(const f16x8*)((const char*)Ks + byt);
            acc[ct] = MFMAH(kf, qf[ks], acc[ct]);    // swapped
        }
    }

    #pragma unroll
    for (int ct = 0; ct < 4; ++ct) {
        const u16* apu = (const u16*)&ap4[ct];
        float4 o;
        o.x = __expf(acc[ct][0] + h2f(apu[0]) - fml.x) * fml.y;
        o.y = __expf(acc[ct][1] + h2f(apu[1]) - fml.x) * fml.y;
        o.z = __expf(acc[ct][2] + h2f(apu[2]) - fml.x) * fml.y;
        o.w = __expf(acc[ct][3] + h2f(apu[3]) - fml.x) * fml.y;
        *(float4*)(S + (size_t)trow * T + s0 + 16 * ct + 4 * a) = o;
    }
}

// ---------------------------------------------------------------------------
// y = Ych(fp16) @ Woutb(fp16)^T via MFMA with LDS staging (validated r14/r15)
// ---------------------------------------------------------------------------
__global__ __launch_bounds__(256) void gemm_out_mfma(
    const u16* __restrict__ Ych, const u16* __restrict__ Wb,
    float* __restrict__ y)
{
    __shared__ u16 As[4096];
    __shared__ u16 Bs[4096];

    const int n0 = blockIdx.x * 64, t0 = blockIdx.y * 64;
    const int tid = threadIdx.x, w = tid >> 6, lane = tid & 63;
    const int b = lane & 15, a = lane >> 4;

    const int srow = tid >> 2, sc16 = (tid & 3) * 16;
    const int swz = (srow & 7) << 4;
    const int sb0 = (srow * 128 + sc16 * 2) ^ swz;
    const int sb1 = (srow * 128 + sc16 * 2 + 16) ^ swz;

    f32x4 acc[4];
    #pragma unroll
    for (int ct = 0; ct < 4; ++ct) acc[ct] = (f32x4){0.f, 0.f, 0.f, 0.f};

    for (int kc = 0; kc < Dm; kc += 64) {
        __syncthreads();
        {
            const u16* ga = Ych + (size_t)(t0 + srow) * Dm + kc + sc16;
            const u16* gb = Wb  + (size_t)(n0 + srow) * Dm + kc + sc16;
            *(int4*)((char*)As + sb0) = *(const int4*)ga;
            *(int4*)((char*)As + sb1) = *(const int4*)(ga + 8);
            *(int4*)((char*)Bs + sb0) = *(const int4*)gb;
            *(int4*)((char*)Bs + sb1) = *(const int4*)(gb + 8);
        }
        __syncthreads();

        f16x8 af[2];
        #pragma unroll
        for (int ks = 0; ks < 2; ++ks) {
            int row = 16 * w + b;
            int byt = (row * 128 + ks * 64 + a * 16) ^ ((row & 7) << 4);
            af[ks] = *(const f16x8*)((const char*)As + byt);
        }
        __builtin_amdgcn_s_setprio(1);
        #pragma unroll
        for (int ct = 0; ct < 4; ++ct) {
            #pragma unroll
            for (int ks = 0; ks < 2; ++ks) {
                int row = 16 * ct + b;
                int byt = (row * 128 + ks * 64 + a * 16) ^ ((row & 7) << 4);
                f16x8 bw = *(const f16x8*)((const char*)Bs + byt);
                acc[ct] = MFMAH(af[ks], bw, acc[ct]);
            }
        }
        __builtin_amdgcn_s_setprio(0);
    }

    #pragma unroll
    for (int r = 0; r < 4; ++r) {
        int t = t0 + 16 * w + a * 4 + r;
        #pragma unroll
        for (int ct = 0; ct < 4; ++ct)
            y[(size_t)t * Dm + n0 + 16 * ct + b] = acc[ct][r];
    }
}

// ---------------------------------------------------------------------------
extern "C" void kernel_launch(void* const* d_in, const int* in_sizes, int n_in,
                              void* d_out, int out_size, void* d_ws, size_t ws_size,
                              hipStream_t stream)
{
    const float* x    = (const float*)d_in[0];
    const float* Wq   = (const float*)d_in[1];
    const float* Wk   = (const float*)d_in[2];
    const float* Wv   = (const float*)d_in[3];
    const float* Wout = (const float*)d_in[4];

    float* out      = (float*)d_out;
    float* y_out    = out;
    float* attn_out = out + (long)T * Dm;     // written LAST -> usable scratch

    // ---- workspace layout (~26 MB; 34.3 MB proven) ----
    char* ws = (char*)d_ws;
    const size_t MB = 1024 * 1024;
    float* invfreq = (float*)ws;                       // 8 KB
    u16* Qh = (u16*)(ws + 8192);                       // 4 MB
    u16* Kh = (u16*)(ws + 8192 + 4 * MB);              // 4 MB
    u16* Vt = (u16*)(ws + 8192 + 8 * MB);              // 4 MB
    char* C = ws + 8192 + 12 * MB;
    u16* xh  = (u16*)(C);                              // phase 1: 4 MB
    u16* Wtb = (u16*)(C + 4 * MB);                     //          6 MB
    u16* APt   = (u16*)(C);                            // phase 2: 8 MB ([t][s])
    u16* Ych   = (u16*)(C + 8 * MB);                   //          4 MB
    u16* Woutb = (u16*)(C + 12 * MB);                  //          2 MB
    float2* mlfinal = (float2*)(C + 14 * MB);          //          16 KB
    // split-K partials in d_out attn region (overwritten later by score):
    u16*    Opart = (u16*)attn_out;                    // 8 MB
    float2* mlbuf = (float2*)((char*)attn_out + 8 * MB); // 512 KB
    (void)ws_size;

    invfreq_kernel<<<dim3(8), dim3(256), 0, stream>>>(invfreq);

    xconv_kernel<<<dim3((T * Dm / 4) / 256), dim3(256), 0, stream>>>(x, xh);
    wtrans_kernel<<<dim3(Dm / 64, NH, 3), dim3(256), 0, stream>>>(Wq, Wk, Wv, Wtb);

    proj_mfma<<<dim3(T / 64, NH), dim3(256), 0, stream>>>(xh, Wtb, Qh, Kh, Vt);

    ap_kernel<<<dim3(T / 512, T), dim3(256), 0, stream>>>(invfreq, APt);
    wout_conv_kernel<<<dim3((Dm * Dm / 4) / 256), dim3(256), 0, stream>>>(Wout, Woutb);

    flash_mfma_split<<<dim3(T / 64, NH, 2), dim3(256), 0, stream>>>(
        Qh, Kh, Vt, APt, Opart, mlbuf);
    flash_combine<<<dim3(NH * T * 8 / 256), dim3(256), 0, stream>>>(
        Opart, mlbuf, Ych, mlfinal);

    // head-15 attention map with fused softmax (overwrites scratch region)
    score_mfma<<<dim3(T / 64, T / 64), dim3(256), 0, stream>>>(
        Qh, Kh, APt, mlfinal, attn_out);

    gemm_out_mfma<<<dim3(Dm / 64, T / 64), dim3(256), 0, stream>>>(Ych, Woutb, y_out);
}